// Round 14
// baseline (112.315 us; speedup 1.0000x reference)
//
#include <hip/hip_runtime.h>
#include <cstdint>
#include <cstddef>

#define BS 8
#define NQ 16384
#define NG 1024
#define NC 5
#define SHARDS 32           // shards per batch; grid = BS*SHARDS = 256 = 1 block/CU
#define SQ 512              // queries per shard
#define CAPC 192            // per-class LDS candidate list capacity
#define CHUNKS 8            // gt merge-chunks per batch (128 gts each)
#define SLACK 0.1514214f    // 0.1*sqrt(2) + 0.01 fp margin
#define FINF 3.0e38f

using u64 = unsigned long long;
typedef unsigned int u32;
#define AGENT __HIP_MEMORY_SCOPE_AGENT

__device__ __forceinline__ u64 aload_u64(const u64* p) {
    return __hip_atomic_load(p, __ATOMIC_RELAXED, AGENT);
}
__device__ __forceinline__ void astore_u64(u64* p, u64 v) {
    __hip_atomic_store(p, v, __ATOMIC_RELAXED, AGENT);
}

// ---------- float top-4 (keep 4 smallest, sorted ascending) ----------
__device__ __forceinline__ void fce(float &x, float &y) {
    float lo = fminf(x, y), hi = fmaxf(x, y);
    x = lo; y = hi;
}
__device__ __forceinline__ void finsert(float k[4], float v) {
    float c = v, t;
    t = fminf(k[0], c); c = fmaxf(k[0], c); k[0] = t;
    t = fminf(k[1], c); c = fmaxf(k[1], c); k[1] = t;
    t = fminf(k[2], c); c = fmaxf(k[2], c); k[2] = t;
    k[3] = fminf(k[3], c);
}
__device__ __forceinline__ void fmerge4(float a[4], float b0, float b1, float b2, float b3) {
    float m0 = fminf(a[0], b3), m1 = fminf(a[1], b2), m2 = fminf(a[2], b1), m3 = fminf(a[3], b0);
    fce(m0, m2); fce(m1, m3); fce(m0, m1); fce(m2, m3);
    a[0] = m0; a[1] = m1; a[2] = m2; a[3] = m3;
}

// ---------- u64 keyed top-4 (exact, tie-break by low 32 = q) ----------
__device__ __forceinline__ void ce(u64 &x, u64 &y) {
    u64 lo = x < y ? x : y;
    u64 hi = x < y ? y : x;
    x = lo; y = hi;
}
__device__ __forceinline__ void merge4(u64 a[4], u64 b0, u64 b1, u64 b2, u64 b3) {
    u64 m0 = a[0] < b3 ? a[0] : b3;
    u64 m1 = a[1] < b2 ? a[1] : b2;
    u64 m2 = a[2] < b1 ? a[2] : b1;
    u64 m3 = a[3] < b0 ? a[3] : b0;
    ce(m0, m2); ce(m1, m3); ce(m0, m1); ce(m2, m3);
    a[0] = m0; a[1] = m1; a[2] = m2; a[3] = m3;
}
__device__ __forceinline__ void kinsert_key(u64 kk[4], u64 k) {
    if (k < kk[3]) { kk[3] = k; ce(kk[2], kk[3]); ce(kk[1], kk[2]); ce(kk[0], kk[1]); }
}
__device__ __forceinline__ void kinsert(u64 kk[4], float cost, unsigned q) {
    unsigned uu = __float_as_uint(cost);
    uu ^= ((unsigned)((int)uu >> 31)) | 0x80000000u;
    kinsert_key(kk, ((u64)uu << 32) | q);
}

// exact softmax numerics — identical to all prior passing rounds
#define SOFTMAX5(lg, X0, X1, X2, X3, X4, S)                                     \
    float X0 = (lg)[0], X1 = (lg)[1], X2 = (lg)[2], X3 = (lg)[3], X4 = (lg)[4]; \
    {                                                                           \
        float mx_ = fmaxf(fmaxf(fmaxf(X0, X1), fmaxf(X2, X3)), X4);             \
        X0 = expf(X0 - mx_); X1 = expf(X1 - mx_); X2 = expf(X2 - mx_);          \
        X3 = expf(X3 - mx_); X4 = expf(X4 - mx_);                               \
    }                                                                           \
    float S = X0 + X1 + X2 + X3 + X4;

// One dispatch. Block = (batch b, shard of SQ queries).
//  P1-P4 (R13-validated): exact probs -> shard-local threshold
//  (T = localP4 - SLACK; conservative since localP4 <= globalP4) ->
//  LDS candidate lists (overflow -> exact LDS full-scan fallback) ->
//  per-gt (thread = gt) partial keyed top-4 over this shard ->
//  agent-scope stores to parts[b][g][shard][4].
//  P5: threads 0..7 acq_rel atomicAdd the batch's chunk counters; the block
//  seeing 31 is the LAST finisher for that 128-gt chunk and merges it (P6):
//  8 lanes/gt read 16 coalesced keys each (agent loads; release chain makes
//  all shards' partials visible), 3-level shfl-xor merge, lane 0 writes out.
//  No barrier, no spin: progress-based; merge result order-independent.
__global__ __launch_bounds__(1024, 1) void matcher_kernel(
        const float* __restrict__ pred_coords,   // [BS][NQ][2]
        const float* __restrict__ logits,        // [BS][NQ][NC]
        const float* __restrict__ gt_coords,     // [BS][NG][2]
        const int*   __restrict__ gt_labels,     // [BS][NG]
        const int*   __restrict__ gt_masks,      // [BS][NG]
        u32*         __restrict__ cnt,           // [BS][CHUNKS], pre-zeroed
        u64*         __restrict__ parts,         // [BS][NG][SHARDS][4]
        int*         __restrict__ out)           // [BS][4][NG]
{
    const int tid = threadIdx.x;
    const int wv = tid >> 6, lane = tid & 63;
    const int b = blockIdx.x / SHARDS, shard = blockIdx.x % SHARDS;
    const int q0 = shard * SQ;

    __shared__ float probs[NC][SQ];              // 10 KB
    __shared__ u64   lists[NC][CAPC];            // 7.5 KB
    __shared__ float Tsh[NC];
    __shared__ u32   lcount[NC];
    __shared__ u32   ovfl;
    __shared__ u32   rets[CHUNKS];

    if (tid == 0) ovfl = 0u;
    if (tid < NC) lcount[tid] = 0u;

    // ---- P1: exact probs (one query per thread, tid < SQ) ----
    float p_reg[NC] = {0.f, 0.f, 0.f, 0.f, 0.f};
    if (tid < SQ) {
        const float* lg = logits + ((size_t)b * NQ + q0 + tid) * NC;
        SOFTMAX5(lg, x0, x1, x2, x3, x4, s);
        p_reg[0] = x0 / s; p_reg[1] = x1 / s; p_reg[2] = x2 / s;
        p_reg[3] = x3 / s; p_reg[4] = x4 / s;
        #pragma unroll
        for (int c = 0; c < NC; ++c) probs[c][tid] = p_reg[c];
    }
    __syncthreads();

    // ---- P2: shard-local per-class top-4 -> threshold (waves 0..4) ----
    if (wv < NC) {
        float t4[4] = {FINF, FINF, FINF, FINF};
        #pragma unroll
        for (int i = 0; i < SQ / 64; ++i) finsert(t4, -probs[wv][i * 64 + lane]);
        #pragma unroll
        for (int d = 1; d < 64; d <<= 1) {
            float b0 = __shfl_xor(t4[0], d, 64);
            float b1 = __shfl_xor(t4[1], d, 64);
            float b2 = __shfl_xor(t4[2], d, 64);
            float b3 = __shfl_xor(t4[3], d, 64);
            fmerge4(t4, b0, b1, b2, b3);
        }
        if (lane == 0) Tsh[wv] = -t4[3] - SLACK;     // localP4 - SLACK
    }
    __syncthreads();

    // ---- P3: ballot-append candidates (tid < SQ) ----
    if (tid < SQ) {
        #pragma unroll
        for (int c = 0; c < NC; ++c) {
            bool pass = (p_reg[c] >= Tsh[c]);
            u64 mk = __ballot(pass);
            if (mk) {
                u32 base = 0;
                if (lane == 0) base = atomicAdd(&lcount[c], (u32)__popcll(mk));
                base = __shfl((int)base, 0, 64);
                if (pass) {
                    u32 r = base + (u32)__popcll(mk & ((1ull << lane) - 1ull));
                    if (r < CAPC)
                        lists[c][r] = ((u64)__float_as_uint(p_reg[c]) << 32) | (u32)(q0 + tid);
                }
            }
        }
    }
    __syncthreads();
    if (tid < NC && lcount[tid] > CAPC) atomicOr(&ovfl, 1u << tid);
    __syncthreads();

    // ---- P4: per-gt partial keyed top-4 over this shard (thread = gt) ----
    {
        const int g = tid;
        const int m = gt_masks[b * NG + g];
        if (m) {
            int c = gt_labels[b * NG + g];
            float2 gc = reinterpret_cast<const float2*>(gt_coords)[(size_t)b * NG + g];
            float gx = gc.x, gy = gc.y, gb2 = gc.x * gc.x + gc.y * gc.y;
            const float2* pc = reinterpret_cast<const float2*>(pred_coords) + (size_t)b * NQ;
            u64 kk[4] = {~0ull, ~0ull, ~0ull, ~0ull};
            if (!((ovfl >> c) & 1u)) {
                u32 nn = lcount[c];                  // <= CAPC here, >= 4
                for (u32 j = 0; j < nn; ++j) {
                    u64 e = lists[c][j];
                    float p = __uint_as_float((u32)(e >> 32));
                    u32 qq = (u32)(e & 0xFFFFFFFFu);
                    float2 cq = pc[qq];
                    float d2 = fmaxf(cq.x * cq.x + cq.y * cq.y + gb2
                                     - 2.0f * (cq.x * gx + cq.y * gy), 0.0f);
                    kinsert(kk, 0.1f * sqrtf(d2) - p, qq);
                }
            } else {
                // overflow fallback: scan ALL shard probs from LDS (still exact)
                for (int j = 0; j < SQ; ++j) {
                    float p = probs[c][j];
                    u32 qq = (u32)(q0 + j);
                    float2 cq = pc[qq];
                    float d2 = fmaxf(cq.x * cq.x + cq.y * cq.y + gb2
                                     - 2.0f * (cq.x * gx + cq.y * gy), 0.0f);
                    kinsert(kk, 0.1f * sqrtf(d2) - p, qq);
                }
            }
            u64* dst = parts + ((size_t)((b << 10) | g)) * (SHARDS * 4) + shard * 4;
            astore_u64(dst + 0, kk[0]);
            astore_u64(dst + 1, kk[1]);
            astore_u64(dst + 2, kk[2]);
            astore_u64(dst + 3, kk[3]);
        }
    }
    __syncthreads();                                 // drains all partial stores

    // ---- P5: publish (release) + last-finisher detection per chunk ----
    if (tid < CHUNKS)
        rets[tid] = __hip_atomic_fetch_add(&cnt[b * CHUNKS + tid], 1u,
                                           __ATOMIC_ACQ_REL, AGENT);
    __syncthreads();

    // ---- P6: merge chunks this block finished last (8 lanes per gt) ----
    const int sub = tid & 7;
    const int gloc = tid >> 3;                       // 0..127
    for (int c = 0; c < CHUNKS; ++c) {
        if (rets[c] == SHARDS - 1) {
            int g = c * 128 + gloc;
            int m = gt_masks[b * NG + g];
            u64 kk[4] = {~0ull, ~0ull, ~0ull, ~0ull};
            if (m) {
                const u64* src = parts + ((size_t)((b << 10) | g)) * (SHARDS * 4) + sub * 16;
                #pragma unroll
                for (int j = 0; j < 16; ++j) kinsert_key(kk, aload_u64(&src[j]));
                #pragma unroll
                for (int d = 1; d < 8; d <<= 1) {    // stays inside 8-lane group
                    u64 b0 = __shfl_xor(kk[0], d, 64);
                    u64 b1 = __shfl_xor(kk[1], d, 64);
                    u64 b2 = __shfl_xor(kk[2], d, 64);
                    u64 b3 = __shfl_xor(kk[3], d, 64);
                    merge4(kk, b0, b1, b2, b3);
                }
            }
            if (sub == 0) {
                #pragma unroll
                for (int j = 0; j < 4; ++j)
                    out[((size_t)(b * 4 + j) << 10) + g] = m ? (int)(kk[j] & 0xFFFFFFFFull) : j;
            }
        }
    }
}

extern "C" void kernel_launch(void* const* d_in, const int* in_sizes, int n_in,
                              void* d_out, int out_size, void* d_ws, size_t ws_size,
                              hipStream_t stream) {
    const float* pred_coords = (const float*)d_in[0];
    const float* pred_logits = (const float*)d_in[1];
    const float* gt_coords   = (const float*)d_in[2];
    const int*   gt_labels   = (const int*)d_in[3];
    const int*   gt_masks    = (const int*)d_in[4];
    int* out = (int*)d_out;

    char* ws = (char*)d_ws;
    u32* cnt   = (u32*)ws;                 // 64 u32, re-zeroed each replay
    u64* parts = (u64*)(ws + 4096);        // 8*1024*32*4*8 = 8.39 MB

    hipMemsetAsync(cnt, 0, 256, stream);
    matcher_kernel<<<BS * SHARDS, 1024, 0, stream>>>(
        pred_coords, pred_logits, gt_coords, gt_labels, gt_masks, cnt, parts, out);
}

// Round 15
// 69.502 us; speedup vs baseline: 1.6160x; 1.6160x over previous
//
#include <hip/hip_runtime.h>
#include <cstdint>
#include <cstddef>

#define BS 8
#define NQ 16384
#define NG 1024
#define NC 5
#define SHARDS 16           // shards per batch; grid = BS*SHARDS = 128 blocks
#define SQ 1024             // queries per shard = one per thread
#define CAPC 256            // per-class candidate capacity
#define LPAD 260            // padded stride (2080 B -> banks spread by 8)
#define CHUNKS 8            // gt merge-chunks per batch (128 gts each)
#define CPAD 32             // counter padding: 32 u32 = 128 B per counter
#define SLACK 0.1514214f    // 0.1*sqrt(2) + 0.01 fp margin
#define FINF 3.0e38f

using u64 = unsigned long long;
typedef unsigned int u32;
#define AGENT __HIP_MEMORY_SCOPE_AGENT

__device__ __forceinline__ u64 aload_u64(const u64* p) {
    return __hip_atomic_load(p, __ATOMIC_RELAXED, AGENT);
}
__device__ __forceinline__ void astore_u64(u64* p, u64 v) {
    __hip_atomic_store(p, v, __ATOMIC_RELAXED, AGENT);
}

// ---------- float top-4 (keep 4 smallest, sorted ascending) ----------
__device__ __forceinline__ void fce(float &x, float &y) {
    float lo = fminf(x, y), hi = fmaxf(x, y);
    x = lo; y = hi;
}
__device__ __forceinline__ void finsert(float k[4], float v) {
    float c = v, t;
    t = fminf(k[0], c); c = fmaxf(k[0], c); k[0] = t;
    t = fminf(k[1], c); c = fmaxf(k[1], c); k[1] = t;
    t = fminf(k[2], c); c = fmaxf(k[2], c); k[2] = t;
    k[3] = fminf(k[3], c);
}
__device__ __forceinline__ void fmerge4(float a[4], float b0, float b1, float b2, float b3) {
    float m0 = fminf(a[0], b3), m1 = fminf(a[1], b2), m2 = fminf(a[2], b1), m3 = fminf(a[3], b0);
    fce(m0, m2); fce(m1, m3); fce(m0, m1); fce(m2, m3);
    a[0] = m0; a[1] = m1; a[2] = m2; a[3] = m3;
}

// ---------- u64 keyed top-4 (exact, tie-break by low 32 = q) ----------
__device__ __forceinline__ void ce(u64 &x, u64 &y) {
    u64 lo = x < y ? x : y;
    u64 hi = x < y ? y : x;
    x = lo; y = hi;
}
__device__ __forceinline__ void merge4(u64 a[4], u64 b0, u64 b1, u64 b2, u64 b3) {
    u64 m0 = a[0] < b3 ? a[0] : b3;
    u64 m1 = a[1] < b2 ? a[1] : b2;
    u64 m2 = a[2] < b1 ? a[2] : b1;
    u64 m3 = a[3] < b0 ? a[3] : b0;
    ce(m0, m2); ce(m1, m3); ce(m0, m1); ce(m2, m3);
    a[0] = m0; a[1] = m1; a[2] = m2; a[3] = m3;
}
__device__ __forceinline__ void kinsert_key(u64 kk[4], u64 k) {
    if (k < kk[3]) { kk[3] = k; ce(kk[2], kk[3]); ce(kk[1], kk[2]); ce(kk[0], kk[1]); }
}
__device__ __forceinline__ void kinsert(u64 kk[4], float cost, unsigned q) {
    unsigned uu = __float_as_uint(cost);
    uu ^= ((unsigned)((int)uu >> 31)) | 0x80000000u;
    kinsert_key(kk, ((u64)uu << 32) | q);
}

// exact softmax numerics — identical to all prior passing rounds
#define SOFTMAX5(lg, X0, X1, X2, X3, X4, S)                                     \
    float X0 = (lg)[0], X1 = (lg)[1], X2 = (lg)[2], X3 = (lg)[3], X4 = (lg)[4]; \
    {                                                                           \
        float mx_ = fmaxf(fmaxf(fmaxf(X0, X1), fmaxf(X2, X3)), X4);             \
        X0 = expf(X0 - mx_); X1 = expf(X1 - mx_); X2 = expf(X2 - mx_);          \
        X3 = expf(X3 - mx_); X4 = expf(X4 - mx_);                               \
    }                                                                           \
    float S = X0 + X1 + X2 + X3 + X4;

// One dispatch. Block = (batch b, shard of SQ=1024 queries); 1024 threads.
//  P1: every thread computes its query's 5 exact probs -> LDS + registers.
//  P2: waves 0..4: shard-local per-class top-4 -> T_c = localP4 - SLACK.
//      Conservative: global-4th-cost <= shard-4th <= 0.1*sqrt(2) - localP4,
//      so any global-top-4 member in this shard has p_c >= localP4 - 0.1√2 > T.
//  P3: ballot-append (p,q) to lists[c]; >=4 guaranteed; overflow -> flag.
//  P4: thread = gt: partial keyed top-4 over lists[label] (or full shard
//      LDS prob scan if flagged) -> agent stores to parts[b][g][shard][4].
//  P5: tid<CHUNKS: acq_rel fetch_add on 128B-PADDED chunk counter (the R14
//      fix: per-line RMW depth = SHARDS, not 1024). Return SHARDS-1 = this
//      block is the last finisher for that 128-gt chunk.
//  P6: last finisher merges: 8 lanes/gt x 8 agent loads, 3-level shfl merge.
//  Keys totally ordered (q in low bits) => merged top-4 = exact global top-4.
__global__ __launch_bounds__(1024, 1) void matcher_kernel(
        const float* __restrict__ pred_coords,   // [BS][NQ][2]
        const float* __restrict__ logits,        // [BS][NQ][NC]
        const float* __restrict__ gt_coords,     // [BS][NG][2]
        const int*   __restrict__ gt_labels,     // [BS][NG]
        const int*   __restrict__ gt_masks,      // [BS][NG]
        u32*         __restrict__ cnt,           // [BS*CHUNKS] x CPAD, pre-zeroed
        u64*         __restrict__ parts,         // [BS][NG][SHARDS][4]
        int*         __restrict__ out)           // [BS][4][NG]
{
    const int tid = threadIdx.x;
    const int wv = tid >> 6, lane = tid & 63;
    const int b = blockIdx.x / SHARDS, shard = blockIdx.x % SHARDS;
    const int q0 = shard * SQ;

    __shared__ float probs[NC][SQ];              // 20 KB
    __shared__ u64   lists[NC * LPAD];           // 10.4 KB, padded stride
    __shared__ float Tsh[NC];
    __shared__ u32   lcount[NC];
    __shared__ u32   ovfl;
    __shared__ u32   rets[CHUNKS];

    if (tid == 0) ovfl = 0u;
    if (tid < NC) lcount[tid] = 0u;

    // ---- P1: exact probs, one query per thread ----
    float p_reg[NC];
    {
        const float* lg = logits + ((size_t)b * NQ + q0 + tid) * NC;
        SOFTMAX5(lg, x0, x1, x2, x3, x4, s);
        p_reg[0] = x0 / s; p_reg[1] = x1 / s; p_reg[2] = x2 / s;
        p_reg[3] = x3 / s; p_reg[4] = x4 / s;
        #pragma unroll
        for (int c = 0; c < NC; ++c) probs[c][tid] = p_reg[c];
    }
    __syncthreads();

    // ---- P2: shard-local per-class top-4 -> threshold (waves 0..4) ----
    if (wv < NC) {
        float t4[4] = {FINF, FINF, FINF, FINF};
        #pragma unroll
        for (int i = 0; i < SQ / 64; ++i) finsert(t4, -probs[wv][i * 64 + lane]);
        #pragma unroll
        for (int d = 1; d < 64; d <<= 1) {
            float b0 = __shfl_xor(t4[0], d, 64);
            float b1 = __shfl_xor(t4[1], d, 64);
            float b2 = __shfl_xor(t4[2], d, 64);
            float b3 = __shfl_xor(t4[3], d, 64);
            fmerge4(t4, b0, b1, b2, b3);
        }
        if (lane == 0) Tsh[wv] = -t4[3] - SLACK;     // localP4 - SLACK
    }
    __syncthreads();

    // ---- P3: ballot-append candidates ----
    {
        #pragma unroll
        for (int c = 0; c < NC; ++c) {
            bool pass = (p_reg[c] >= Tsh[c]);
            u64 mk = __ballot(pass);
            if (mk) {
                u32 base = 0;
                if (lane == 0) base = atomicAdd(&lcount[c], (u32)__popcll(mk));
                base = __shfl((int)base, 0, 64);
                if (pass) {
                    u32 r = base + (u32)__popcll(mk & ((1ull << lane) - 1ull));
                    if (r < CAPC)
                        lists[c * LPAD + r] =
                            ((u64)__float_as_uint(p_reg[c]) << 32) | (u32)(q0 + tid);
                }
            }
        }
    }
    __syncthreads();
    if (tid < NC && lcount[tid] > CAPC) atomicOr(&ovfl, 1u << tid);
    __syncthreads();

    // ---- P4: per-gt partial keyed top-4 over this shard (thread = gt) ----
    {
        const int g = tid;
        const int m = gt_masks[b * NG + g];
        if (m) {
            int c = gt_labels[b * NG + g];
            float2 gc = reinterpret_cast<const float2*>(gt_coords)[(size_t)b * NG + g];
            float gx = gc.x, gy = gc.y, gb2 = gc.x * gc.x + gc.y * gc.y;
            const float2* pc = reinterpret_cast<const float2*>(pred_coords) + (size_t)b * NQ;
            u64 kk[4] = {~0ull, ~0ull, ~0ull, ~0ull};
            if (!((ovfl >> c) & 1u)) {
                u32 nn = lcount[c];                  // <= CAPC here, >= 4
                const u64* lst = lists + c * LPAD;
                for (u32 j = 0; j < nn; ++j) {
                    u64 e = lst[j];
                    float p = __uint_as_float((u32)(e >> 32));
                    u32 qq = (u32)(e & 0xFFFFFFFFu);
                    float2 cq = pc[qq];
                    float d2 = fmaxf(cq.x * cq.x + cq.y * cq.y + gb2
                                     - 2.0f * (cq.x * gx + cq.y * gy), 0.0f);
                    kinsert(kk, 0.1f * sqrtf(d2) - p, qq);
                }
            } else {
                // overflow fallback: scan ALL shard probs from LDS (still exact)
                for (int j = 0; j < SQ; ++j) {
                    float p = probs[c][j];
                    u32 qq = (u32)(q0 + j);
                    float2 cq = pc[qq];
                    float d2 = fmaxf(cq.x * cq.x + cq.y * cq.y + gb2
                                     - 2.0f * (cq.x * gx + cq.y * gy), 0.0f);
                    kinsert(kk, 0.1f * sqrtf(d2) - p, qq);
                }
            }
            u64* dst = parts + ((size_t)((b << 10) | g)) * (SHARDS * 4) + shard * 4;
            astore_u64(dst + 0, kk[0]);
            astore_u64(dst + 1, kk[1]);
            astore_u64(dst + 2, kk[2]);
            astore_u64(dst + 3, kk[3]);
        }
    }
    __syncthreads();                                 // drains all partial stores

    // ---- P5: publish (release) + last-finisher detection (padded counters) ----
    if (tid < CHUNKS)
        rets[tid] = __hip_atomic_fetch_add(&cnt[(b * CHUNKS + tid) * CPAD], 1u,
                                           __ATOMIC_ACQ_REL, AGENT);
    __syncthreads();

    // ---- P6: merge chunks this block finished last (8 lanes per gt) ----
    const int sub = tid & 7;
    const int gloc = tid >> 3;                       // 0..127
    for (int c = 0; c < CHUNKS; ++c) {
        if (rets[c] == SHARDS - 1) {
            int g = c * 128 + gloc;
            int m = gt_masks[b * NG + g];
            u64 kk[4] = {~0ull, ~0ull, ~0ull, ~0ull};
            if (m) {
                const u64* src = parts + ((size_t)((b << 10) | g)) * (SHARDS * 4) + sub * 8;
                #pragma unroll
                for (int j = 0; j < 8; ++j) kinsert_key(kk, aload_u64(&src[j]));
                #pragma unroll
                for (int d = 1; d < 8; d <<= 1) {    // stays inside 8-lane group
                    u64 b0 = __shfl_xor(kk[0], d, 64);
                    u64 b1 = __shfl_xor(kk[1], d, 64);
                    u64 b2 = __shfl_xor(kk[2], d, 64);
                    u64 b3 = __shfl_xor(kk[3], d, 64);
                    merge4(kk, b0, b1, b2, b3);
                }
            }
            if (sub == 0) {
                #pragma unroll
                for (int j = 0; j < 4; ++j)
                    out[((size_t)(b * 4 + j) << 10) + g] = m ? (int)(kk[j] & 0xFFFFFFFFull) : j;
            }
        }
    }
}

extern "C" void kernel_launch(void* const* d_in, const int* in_sizes, int n_in,
                              void* d_out, int out_size, void* d_ws, size_t ws_size,
                              hipStream_t stream) {
    const float* pred_coords = (const float*)d_in[0];
    const float* pred_logits = (const float*)d_in[1];
    const float* gt_coords   = (const float*)d_in[2];
    const int*   gt_labels   = (const int*)d_in[3];
    const int*   gt_masks    = (const int*)d_in[4];
    int* out = (int*)d_out;

    char* ws = (char*)d_ws;
    u32* cnt   = (u32*)ws;                 // 64 counters x 128B = 8 KB, zeroed each replay
    u64* parts = (u64*)(ws + 16384);       // 8*1024*16*4*8 = 4.19 MB

    hipMemsetAsync(cnt, 0, BS * CHUNKS * CPAD * sizeof(u32), stream);
    matcher_kernel<<<BS * SHARDS, 1024, 0, stream>>>(
        pred_coords, pred_logits, gt_coords, gt_labels, gt_masks, cnt, parts, out);
}

// Round 16
// 28.375 us; speedup vs baseline: 3.9582x; 2.4494x over previous
//
#include <hip/hip_runtime.h>
#include <cstdint>
#include <cstddef>

#define BS 8
#define NQ 16384
#define NG 1024
#define NC 5
#define BPB 32              // blocks per batch -> grid 256 = 1 block/CU
#define LCAP 12032          // stage-1 packed candidate list (48 KB LDS)
#define CAP 400             // per-class exact candidate list (16 KB LDS)
#define PREF 0.55f          // static argmax-prob prefilter
#define SLACK 0.1514214f    // 0.1*sqrt(2) + 0.01 margin
#define B2EPS 1e-3f         // quantization/fast-math slop on the list filter

using u64 = unsigned long long;
typedef unsigned int u32;

// ---------- u64 keyed top-4 (exact, tie-break by low 32 = q) ----------
__device__ __forceinline__ void ce(u64 &x, u64 &y) {
    u64 lo = x < y ? x : y;
    u64 hi = x < y ? y : x;
    x = lo; y = hi;
}
__device__ __forceinline__ void merge4(u64 a[4], u64 b0, u64 b1, u64 b2, u64 b3) {
    u64 m0 = a[0] < b3 ? a[0] : b3;
    u64 m1 = a[1] < b2 ? a[1] : b2;
    u64 m2 = a[2] < b1 ? a[2] : b1;
    u64 m3 = a[3] < b0 ? a[3] : b0;
    ce(m0, m2); ce(m1, m3); ce(m0, m1); ce(m2, m3);
    a[0] = m0; a[1] = m1; a[2] = m2; a[3] = m3;
}
__device__ __forceinline__ void kinsert(u64 kk[4], float cost, unsigned q) {
    unsigned uu = __float_as_uint(cost);
    uu ^= ((unsigned)((int)uu >> 31)) | 0x80000000u;
    u64 k = ((u64)uu << 32) | q;
    if (k < kk[3]) { kk[3] = k; ce(kk[2], kk[3]); ce(kk[1], kk[2]); ce(kk[0], kk[1]); }
}

// ---------- u32 descending top-4 (for packed keys) ----------
__device__ __forceinline__ u32 umaxu(u32 a, u32 b) { return a > b ? a : b; }
__device__ __forceinline__ u32 uminu(u32 a, u32 b) { return a < b ? a : b; }
__device__ __forceinline__ void uce_desc(u32 &x, u32 &y) {
    u32 hi = umaxu(x, y), lo = uminu(x, y); x = hi; y = lo;
}
__device__ __forceinline__ void uinsert_desc(u32 k[4], u32 v) {
    u32 t;
    t = umaxu(k[0], v); v = uminu(k[0], v); k[0] = t;
    t = umaxu(k[1], v); v = uminu(k[1], v); k[1] = t;
    t = umaxu(k[2], v); v = uminu(k[2], v); k[2] = t;
    k[3] = umaxu(k[3], v);
}
__device__ __forceinline__ void umerge4_desc(u32 a[4], u32 b0, u32 b1, u32 b2, u32 b3) {
    u32 m0 = umaxu(a[0], b3), m1 = umaxu(a[1], b2), m2 = umaxu(a[2], b1), m3 = umaxu(a[3], b0);
    uce_desc(m0, m2); uce_desc(m1, m3); uce_desc(m0, m1); uce_desc(m2, m3);
    a[0] = m0; a[1] = m1; a[2] = m2; a[3] = m3;
}

// exact softmax numerics — identical to all prior passing rounds
#define SOFTMAX5(lg, X0, X1, X2, X3, X4, S)                                     \
    float X0 = (lg)[0], X1 = (lg)[1], X2 = (lg)[2], X3 = (lg)[3], X4 = (lg)[4]; \
    {                                                                           \
        float mx_ = fmaxf(fmaxf(fmaxf(X0, X1), fmaxf(X2, X3)), X4);             \
        X0 = expf(X0 - mx_); X1 = expf(X1 - mx_); X2 = expf(X2 - mx_);          \
        X3 = expf(X3 - mx_); X4 = expf(X4 - mx_);                               \
    }                                                                           \
    float S = X0 + X1 + X2 + X3 + X4;

// Single-pass argmax prune (best-measured configuration, R10):
//  P1: one scan; per q: p* = rcp(sum) (argmax prob, fast), pack (p15,c*,q) u32
//      into LDS list L if p* >= PREF.
//  A2: per-class top-4 of L -> T_c = P4_est - SLACK. Flags (-> exact brute
//      for that class's gts) when: L overflow, class count<4, T_c < PREF,
//      or per-class CAP overflow. Correctness: candidate (q,c) needs
//      p_c >= T_c > 0.5 => c is q's argmax AND p* >= PREF => q in L.
//      P4_est from argmax-subset, quantized down => <= true P4*. All
//      approx errors (rcp/quant ~2e-5) sit inside SLACK's 0.01 spare.
//  B2: filter L (+B2EPS slop); accepted entries get EXACT p (expf + x/s,
//      bit-identical to prior rounds) into lists[c].
//  C : exact keyed top-4 per gt over lists[c] (or brute if flagged).
__global__ __launch_bounds__(1024, 1) void fused_kernel(
        const float* __restrict__ pred_coords,   // [BS][NQ][2]
        const float* __restrict__ logits,        // [BS][NQ][NC]
        const float* __restrict__ gt_coords,     // [BS][NG][2]
        const int*   __restrict__ gt_labels,     // [BS][NG]
        const int*   __restrict__ gt_masks,      // [BS][NG]
        int*         __restrict__ out)           // [BS][4][NG]
{
    const int tid = threadIdx.x;
    const int wv = tid >> 6, lane = tid & 63;    // 16 waves
    const int b = blockIdx.x / BPB, part = blockIdx.x % BPB;

    __shared__ u64  lists[NC][CAP];              // 16000 B (8B-aligned first)
    __shared__ u32  L[LCAP];                     // 48128 B
    __shared__ u32  a2buf[15][4];
    __shared__ u32  a2cnt[15];
    __shared__ float Tsh[NC];
    __shared__ u32  lcount[NC];
    __shared__ u32  lcnt;
    __shared__ u32  flags;

    if (tid == 0) { lcnt = 0u; flags = 0u; }
    if (tid < NC) lcount[tid] = 0u;
    __syncthreads();

    const float* lgb = logits + (size_t)b * NQ * NC;

    // ---------------- pass 1: single scan, argmax prob only ----------------
    #pragma unroll 2
    for (int r = 0; r < 16; ++r) {
        int q = r * 1024 + tid;
        const float* lg = lgb + (size_t)q * NC;
        float l0 = lg[0], l1 = lg[1], l2 = lg[2], l3 = lg[3], l4 = lg[4];
        float m = fmaxf(fmaxf(fmaxf(l0, l1), fmaxf(l2, l3)), l4);
        float e0 = __expf(l0 - m), e1 = __expf(l1 - m), e2 = __expf(l2 - m);
        float e3 = __expf(l3 - m), e4 = __expf(l4 - m);
        float s = ((e0 + e1) + (e2 + e3)) + e4;
        float ps = __builtin_amdgcn_rcpf(s);     // p* (argmax prob, ~3e-6 rel err)
        int cs = (l4 == m) ? 4 : (l3 == m) ? 3 : (l2 == m) ? 2 : (l1 == m) ? 1 : 0;

        bool pass = (ps >= PREF);
        u64 mk = __ballot(pass);
        if (mk) {
            u32 base = 0;
            if (lane == 0) base = atomicAdd(&lcnt, (u32)__popcll(mk));
            base = __shfl((int)base, 0, 64);
            if (pass) {
                u32 fb = __float_as_uint(ps);
                fb = fb > 0x3F7FFFFFu ? 0x3F7FFFFFu : fb;     // clamp p=1.0
                u32 key = (((fb >> 8) & 0x7FFFu) << 17) | ((u32)cs << 14) | (u32)q;
                u32 slot = base + (u32)__popcll(mk & ((1ull << lane) - 1ull));
                if (slot < LCAP) L[slot] = key;
            }
        }
    }
    __syncthreads();

    const u32 n = lcnt < LCAP ? lcnt : LCAP;
    if (tid == 0 && lcnt > LCAP) atomicOr(&flags, 0x1Fu);    // all-brute

    // ---------------- A2a: 15 waves = 5 classes x 3 slices ----------------
    if (wv < 15) {
        int c = wv % 5, sl = wv / 5;
        u32 t4[4] = {0u, 0u, 0u, 0u};
        u32 cnt = 0u;
        for (u32 j = (u32)(sl * 64 + lane); j < n; j += 192u) {
            u32 k = L[j];
            if (((k >> 14) & 7u) == (u32)c) { uinsert_desc(t4, k); ++cnt; }
        }
        #pragma unroll
        for (int d = 1; d < 64; d <<= 1) {
            u32 b0 = (u32)__shfl_xor((int)t4[0], d, 64);
            u32 b1 = (u32)__shfl_xor((int)t4[1], d, 64);
            u32 b2 = (u32)__shfl_xor((int)t4[2], d, 64);
            u32 b3 = (u32)__shfl_xor((int)t4[3], d, 64);
            umerge4_desc(t4, b0, b1, b2, b3);
            cnt += (u32)__shfl_xor((int)cnt, d, 64);
        }
        if (lane == 0) {
            a2buf[wv][0] = t4[0]; a2buf[wv][1] = t4[1];
            a2buf[wv][2] = t4[2]; a2buf[wv][3] = t4[3];
            a2cnt[wv] = cnt;
        }
    }
    __syncthreads();

    // ---------------- A2b: final per-class threshold ----------------
    if (tid < NC) {
        u32 t4[4] = {a2buf[tid][0], a2buf[tid][1], a2buf[tid][2], a2buf[tid][3]};
        umerge4_desc(t4, a2buf[tid + 5][0], a2buf[tid + 5][1], a2buf[tid + 5][2], a2buf[tid + 5][3]);
        umerge4_desc(t4, a2buf[tid + 10][0], a2buf[tid + 10][1], a2buf[tid + 10][2], a2buf[tid + 10][3]);
        u32 cnt = a2cnt[tid] + a2cnt[tid + 5] + a2cnt[tid + 10];
        float p4 = __uint_as_float(0x3F000000u | ((t4[3] >> 17) << 8));  // <= true P4*
        float T = p4 - SLACK;
        Tsh[tid] = T;
        if (cnt < 4u || T < PREF) atomicOr(&flags, 1u << tid);
    }
    __syncthreads();

    // ---------------- B2: filter L; exact p for accepted ----------------
    {
        u32 fl = flags;
        for (u32 j = (u32)tid; j < n; j += 1024u) {
            u32 k = L[j];
            u32 c = (k >> 14) & 7u;
            if ((fl >> c) & 1u) continue;
            float pf = __uint_as_float(0x3F000000u | ((k >> 17) << 8));
            if (pf >= Tsh[c] - B2EPS) {
                u32 q = k & 0x3FFFu;
                const float* lg = lgb + (size_t)q * NC;
                SOFTMAX5(lg, x0, x1, x2, x3, x4, s);
                float num = (c == 0) ? x0 : (c == 1) ? x1 : (c == 2) ? x2 : (c == 3) ? x3 : x4;
                float pe = num / s;              // exact numerics (matches prior rounds)
                u32 slot = atomicAdd(&lcount[c], 1u);
                if (slot < CAP) lists[c][slot] = ((u64)__float_as_uint(pe) << 32) | q;
            }
        }
    }
    __syncthreads();
    if (tid < NC && lcount[tid] > CAP) atomicOr(&flags, 1u << tid);
    __syncthreads();

    // ---------------- phase C: exact keyed top-4 per gt (2 gts/wave) ----------------
    const float2* pc = reinterpret_cast<const float2*>(pred_coords) + (size_t)b * NQ;
    const u32 fl2 = flags;
    #pragma unroll 1
    for (int i = 0; i < 2; ++i) {
        int g = part * (NG / BPB) + i * 16 + wv;
        int m = gt_masks[b * NG + g];
        u64 kk[4] = {~0ull, ~0ull, ~0ull, ~0ull};
        if (m) {
            int c = gt_labels[b * NG + g];
            float2 gc = reinterpret_cast<const float2*>(gt_coords)[(size_t)b * NG + g];
            float gx = gc.x, gy = gc.y, gb2 = gc.x * gc.x + gc.y * gc.y;
            if (!((fl2 >> c) & 1u)) {
                u32 nn = lcount[c] < CAP ? lcount[c] : CAP;
                for (u32 j = (u32)lane; j < nn; j += 64u) {
                    u64 e = lists[c][j];
                    float p = __uint_as_float((unsigned)(e >> 32));
                    unsigned qq = (unsigned)(e & 0xFFFFFFFFu);
                    float2 cq = pc[qq];
                    float d2 = fmaxf(cq.x * cq.x + cq.y * cq.y + gb2
                                     - 2.0f * (cq.x * gx + cq.y * gy), 0.0f);
                    kinsert(kk, 0.1f * sqrtf(d2) - p, qq);
                }
            } else {
                // flagged class: exact brute scan (same numerics, always correct)
                for (int q2 = lane; q2 < NQ; q2 += 64) {
                    const float* lg2 = lgb + (size_t)q2 * NC;
                    SOFTMAX5(lg2, y0, y1, y2, y3, y4, s2);
                    float num = (c == 0) ? y0 : (c == 1) ? y1 : (c == 2) ? y2 : (c == 3) ? y3 : y4;
                    float p = num / s2;
                    float2 cq = pc[q2];
                    float d2 = fmaxf(cq.x * cq.x + cq.y * cq.y + gb2
                                     - 2.0f * (cq.x * gx + cq.y * gy), 0.0f);
                    kinsert(kk, 0.1f * sqrtf(d2) - p, (unsigned)q2);
                }
            }
            #pragma unroll
            for (int d = 1; d < 64; d <<= 1) {
                u64 b0 = __shfl_xor(kk[0], d, 64);
                u64 b1 = __shfl_xor(kk[1], d, 64);
                u64 b2_ = __shfl_xor(kk[2], d, 64);
                u64 b3 = __shfl_xor(kk[3], d, 64);
                merge4(kk, b0, b1, b2_, b3);
            }
        }
        if (lane < 4) {
            u64 sel = (lane == 0) ? kk[0] : (lane == 1) ? kk[1] : (lane == 2) ? kk[2] : kk[3];
            int idx = m ? (int)(sel & 0xFFFFFFFFull) : lane;
            out[((size_t)(b * 4 + lane) << 10) + g] = idx;
        }
    }
}

extern "C" void kernel_launch(void* const* d_in, const int* in_sizes, int n_in,
                              void* d_out, int out_size, void* d_ws, size_t ws_size,
                              hipStream_t stream) {
    const float* pred_coords = (const float*)d_in[0];
    const float* pred_logits = (const float*)d_in[1];
    const float* gt_coords   = (const float*)d_in[2];
    const int*   gt_labels   = (const int*)d_in[3];
    const int*   gt_masks    = (const int*)d_in[4];
    int* out = (int*)d_out;

    fused_kernel<<<BS * BPB, 1024, 0, stream>>>(
        pred_coords, pred_logits, gt_coords, gt_labels, gt_masks, out);
}